// Round 3
// baseline (2731.980 us; speedup 1.0000x reference)
//
#include <hip/hip_runtime.h>

// LongBlock on MI355X (gfx950). Input dtype (f32 vs bf16) is AUTO-DETECTED at
// runtime (device-side flag). All intermediates are canonical bf16 (weights
// transposed+converted once per call). Output dtype follows the input flag.
// Pipeline: ln1 -> conv+silu -> {q,k,v,ig,og} GEMMs (bf16 MFMA, B^T staged) ->
// per-head norms -> chunked gated scan -> fused attn epilogue -> Wo GEMM(+x) ->
// ln2 -> MLP (gate GEMM, val GEMM w/ fused silu*mul, out GEMM w/ resid).
// GEMM: 128x128 tile, BK=32, 4 waves (2Mx2N, 64x64/wave), 32 KiB dbuf LDS ->
// 4 resident blocks/CU (cross-block latency hiding, m114 mechanism).
// Schedule: T3-minimum {stage t+1 -> ds_read t -> MFMA -> vmcnt(0) -> barrier}.
// LDS XOR swizzle slot^=( row>>1)&3 via pre-swizzled global source (linear
// gload_lds dest) + same XOR on ds_read (conflicts measured 0 for this family).
// Chunked-XCD block swizzle (m-fast within n-stripe): each XCD pins one
// B-panel in its private L2 and streams A -> cuts L2-miss FETCH traffic.
// Workspace: liveness-packed arena, peak 256 MiB (8 slots x 32 MiB).

#define D_MODEL 2048
#define NHEADS 16
#define HEADDIM 128
#define FFDIM 8192
#define BSZ 2
#define TLEN 4096
#define MTOK (BSZ * TLEN)
#define CHUNK 128
#define NCHUNK (TLEN / CHUNK)

typedef unsigned short u16;
typedef __attribute__((ext_vector_type(8))) short bf16x8;
typedef __attribute__((ext_vector_type(4))) float f32x4;

__device__ __forceinline__ float bf2f(unsigned u) {
    u <<= 16;
    float f;
    __builtin_memcpy(&f, &u, 4);
    return f;
}
__device__ __forceinline__ u16 f2bf(float f) {
    unsigned u;
    __builtin_memcpy(&u, &f, 4);
    u = u + 0x7fffu + ((u >> 16) & 1u);   // RNE
    return (u16)(u >> 16);
}
__device__ __forceinline__ void unpack8(uint4 p, float* v) {
    v[0] = bf2f(p.x & 0xffffu); v[1] = bf2f(p.x >> 16);
    v[2] = bf2f(p.y & 0xffffu); v[3] = bf2f(p.y >> 16);
    v[4] = bf2f(p.z & 0xffffu); v[5] = bf2f(p.z >> 16);
    v[6] = bf2f(p.w & 0xffffu); v[7] = bf2f(p.w >> 16);
}
__device__ __forceinline__ uint4 pack8(const float* v) {
    uint4 p;
    p.x = (unsigned)f2bf(v[0]) | ((unsigned)f2bf(v[1]) << 16);
    p.y = (unsigned)f2bf(v[2]) | ((unsigned)f2bf(v[3]) << 16);
    p.z = (unsigned)f2bf(v[4]) | ((unsigned)f2bf(v[5]) << 16);
    p.w = (unsigned)f2bf(v[6]) | ((unsigned)f2bf(v[7]) << 16);
    return p;
}
__device__ __forceinline__ float sigmoidf_(float x) { return 1.0f / (1.0f + __expf(-x)); }

// dtype-flag helpers: f != 0 => buffer is float32, else bf16
__device__ __forceinline__ float ld1f(const void* p, size_t i, int f) {
    return f ? ((const float*)p)[i] : bf2f(((const u16*)p)[i]);
}
__device__ __forceinline__ void ld8f(const void* p, size_t i, int f, float* v) {
    if (f) {
        const float4* fp = (const float4*)((const float*)p + i);
        float4 a = fp[0], b = fp[1];
        v[0] = a.x; v[1] = a.y; v[2] = a.z; v[3] = a.w;
        v[4] = b.x; v[5] = b.y; v[6] = b.z; v[7] = b.w;
    } else {
        uint4 q = *(const uint4*)((const u16*)p + i);
        unpack8(q, v);
    }
}

__device__ __forceinline__ void async16(const u16* g, u16* l) {
    __builtin_amdgcn_global_load_lds((const __attribute__((address_space(1))) void*)g,
                                     (__attribute__((address_space(3))) void*)l, 16, 0, 0);
}

// ---------------- dtype detector: count exponent==0xFF u16 patterns in x ----------------
__global__ __launch_bounds__(256) void detect_k(const u16* __restrict__ probe, int* __restrict__ flag) {
    int tid = threadIdx.x;
    int cnt = 0;
    for (int i = tid; i < 16384; i += 256) {
        unsigned e = (probe[i] >> 7) & 0xFFu;
        if (e == 0xFFu) cnt++;
    }
#pragma unroll
    for (int off = 32; off; off >>= 1) cnt += __shfl_xor(cnt, off, 64);
    __shared__ int tot[4];
    if ((tid & 63) == 0) tot[tid >> 6] = cnt;
    __syncthreads();
    if (tid == 0) flag[0] = (tot[0] + tot[1] + tot[2] + tot[3] > 4) ? 1 : 0;
}

__global__ void copyflag_k(const int* __restrict__ a, int* __restrict__ b) { b[0] = a[0]; }

// ---------------- weight transpose+convert: in[K,N] (flagged) -> out[N,K] bf16 ----------------
__global__ __launch_bounds__(256) void transpose_k(const void* __restrict__ in, u16* __restrict__ out,
                                                   int K, int N, const int* __restrict__ fl) {
    int f = *fl;
    __shared__ u16 tile[32][33];
    int n0 = blockIdx.x * 32, k0 = blockIdx.y * 32;
    int tx = threadIdx.x, ty = threadIdx.y;  // (32,8)
#pragma unroll
    for (int j = 0; j < 4; ++j)
        tile[ty + j * 8][tx] = f2bf(ld1f(in, (size_t)(k0 + ty + j * 8) * N + n0 + tx, f));
    __syncthreads();
#pragma unroll
    for (int j = 0; j < 4; ++j)
        out[(size_t)(n0 + ty + j * 8) * K + k0 + tx] = tile[tx][ty + j * 8];
}

// ---------------- LayerNorm over C=2048; block per row ----------------
template <int IN_RAW>
__global__ __launch_bounds__(256) void ln_rows(const void* __restrict__ in, u16* __restrict__ out,
                                               const void* __restrict__ w, const void* __restrict__ bb,
                                               const int* __restrict__ fl) {
    int f = *fl;
    int m = blockIdx.x, tid = threadIdx.x;
    size_t base = (size_t)m * D_MODEL + tid * 8;
    float v[8];
    ld8f(in, base, IN_RAW ? f : 0, v);
    float s = 0.f, ss = 0.f;
#pragma unroll
    for (int i = 0; i < 8; ++i) { s += v[i]; ss += v[i] * v[i]; }
#pragma unroll
    for (int off = 32; off; off >>= 1) { s += __shfl_xor(s, off, 64); ss += __shfl_xor(ss, off, 64); }
    __shared__ float red[8];
    int lane = tid & 63, wvi = tid >> 6;
    if (lane == 0) { red[wvi] = s; red[4 + wvi] = ss; }
    __syncthreads();
    s = red[0] + red[1] + red[2] + red[3];
    ss = red[4] + red[5] + red[6] + red[7];
    float mu = s * (1.f / D_MODEL);
    float var = ss * (1.f / D_MODEL) - mu * mu;
    float rs = rsqrtf(var + 1e-5f);
    int ci = tid * 8;
    float o[8];
#pragma unroll
    for (int i = 0; i < 8; ++i)
        o[i] = (v[i] - mu) * rs * ld1f(w, ci + i, f) + ld1f(bb, ci + i, f);
    *(uint4*)&out[base] = pack8(o);
}

// ---------------- depthwise causal conv K=4 + silu ----------------
__global__ __launch_bounds__(256) void conv_silu_k(const u16* __restrict__ h, const void* __restrict__ cw,
                                                   const void* __restrict__ cb, u16* __restrict__ out,
                                                   const int* __restrict__ fl) {
    int f = *fl;
    int m = blockIdx.x, tid = threadIdx.x;
    int b = m >> 12, t = m & (TLEN - 1);
    int c = tid * 8;
    float acc[8];
#pragma unroll
    for (int i = 0; i < 8; ++i) acc[i] = ld1f(cb, c + i, f);
    float wv[8][4];
#pragma unroll
    for (int i = 0; i < 8; ++i) {
        if (f) {
            float4 wp = *(const float4*)((const float*)cw + (size_t)(c + i) * 4);
            wv[i][0] = wp.x; wv[i][1] = wp.y; wv[i][2] = wp.z; wv[i][3] = wp.w;
        } else {
            uint2 wp = *(const uint2*)((const u16*)cw + (size_t)(c + i) * 4);
            wv[i][0] = bf2f(wp.x & 0xffffu); wv[i][1] = bf2f(wp.x >> 16);
            wv[i][2] = bf2f(wp.y & 0xffffu); wv[i][3] = bf2f(wp.y >> 16);
        }
    }
#pragma unroll
    for (int j = 0; j < 4; ++j) {
        int tj = t - 3 + j;
        if (tj < 0) continue;
        uint4 hp = *(const uint4*)&h[((size_t)(b * TLEN + tj)) * D_MODEL + c];
        float hv[8];
        unpack8(hp, hv);
#pragma unroll
        for (int i = 0; i < 8; ++i) acc[i] += wv[i][j] * hv[i];
    }
    float o[8];
#pragma unroll
    for (int i = 0; i < 8; ++i) o[i] = acc[i] * sigmoidf_(acc[i]);
    *(uint4*)&out[(size_t)m * D_MODEL + c] = pack8(o);
}

// ---------------- bf16 GEMM: C[m,n] = sum_k A[m,k]*BT[n,k] ----------------
// 128x128 tile, BK=32, 256 thr (4 waves 2Mx2N, 64x64/wave), 32 KiB dbuf LDS
// -> up to 4 blocks/CU resident. Per K-tile: {stage t+1 (4x gload_lds) ->
// ds_read cur (8x b128) -> setprio(1) 16 MFMA setprio(0) -> vmcnt(0) ->
// s_barrier}. LDS swizzle: row-major [128][32] u16; 16B-slot s of row r holds
// global chunk s ^ ((r>>1)&3); gload_lds dest LINEAR, global source chunk
// pre-XORed, ds_read applies same XOR (involution). XCD-chunked block swizzle:
// XCD owns gx/8 n-stripes, m-fast within stripe (B-panel L2-resident).
// EPI 0: bf16 store.
// EPI 1: bf16 = sigmoid(acc + rawbias[n])            (aux raw-flagged)
// EPI 2: bf16 = acc + raw_resid[m,n]                 (aux raw-flagged, e.g. x)
// EPI 3: bf16 = silu(bf16 aux[m,n]) * acc            (aux canonical; may alias out)
// EPI 4: out[oofs+m*N+n] = acc + bf16 aux[m,n]; out dtype per flag (f32/bf16)
template <int EPI>
__global__ __launch_bounds__(256, 4) void gemmT(const u16* __restrict__ A, const u16* __restrict__ BT,
                                                void* out, const void* aux, const int* fl,
                                                long long oofs, int M, int N, int K) {
    __shared__ u16 As[2][4096];   // [buf][128 rows][32 k]
    __shared__ u16 Bs[2][4096];
    const int tid = threadIdx.x;
    const int lane = tid & 63;
    const int wv = tid >> 6;       // wave 0..3
    const int wm = wv >> 1;        // 0..1 (64-row band)
    const int wn = wv & 1;         // 0..1 (64-col band)

    // chunked XCD swizzle: xcd owns gx/8 contiguous n-stripes, m-fast within.
    const int gx = gridDim.x, gy = gridDim.y;
    const int flat = blockIdx.y * gx + blockIdx.x;
    const int nxs = gx >> 3;                 // n-stripes per XCD (gx % 8 == 0)
    const int xcd = flat & 7, pos = flat >> 3;
    const int bx = xcd * nxs + pos / gy;
    const int by = pos % gy;
    const int m0 = by * 128, n0 = bx * 128;

    // staging: 2 passes per operand; pass p covers rows p*64+(tid>>2),
    // chunk tid&3; source chunk pre-XORed by ((row>>1)&3) = (tid>>3)&3.
    const int rS = tid >> 2;
    const int cS = (((tid & 3) ^ ((tid >> 3) & 3)) << 3);
    const u16* aB = A + (size_t)(m0 + rS) * K + cS;
    const u16* bB = BT + (size_t)(n0 + rS) * K + cS;

    // fragment read offsets (u16 units): row = w*64 + m*16 + fr, chunk kq;
    // slot = kq ^ ((fr>>1)&3).
    const int fr = lane & 15;
    const int kq = lane >> 4;                // 0..3
    const int sA = ((kq ^ ((fr >> 1) & 3)) << 3);
    const int rdA = (wm * 64 + fr) * 32 + sA;
    const int rdB = (wn * 64 + fr) * 32 + sA;

    f32x4 acc[4][4];
#pragma unroll
    for (int i = 0; i < 4; ++i)
#pragma unroll
        for (int j = 0; j < 4; ++j) acc[i][j] = (f32x4)0.0f;

#define BARX() asm volatile("s_barrier" ::: "memory")
#define WAITV0() asm volatile("s_waitcnt vmcnt(0)" ::: "memory")
#define STG(sel, tI)                                                                     \
    do {                                                                                 \
        const u16* ag_ = aB + (size_t)(tI) * 32;                                         \
        const u16* bg_ = bB + (size_t)(tI) * 32;                                         \
        async16(ag_, &As[sel][tid * 8]);                                                 \
        async16(ag_ + (size_t)64 * K, &As[sel][2048 + tid * 8]);                         \
        async16(bg_, &Bs[sel][tid * 8]);                                                 \
        async16(bg_ + (size_t)64 * K, &Bs[sel][2048 + tid * 8]);                         \
    } while (0)

    STG(0, 0);
    WAITV0();
    BARX();

    const int NT = K >> 5;
    int cur = 0;
    for (int t = 0; t < NT; ++t) {
        if (t + 1 < NT) {
            if (cur) STG(0, t + 1);
            else     STG(1, t + 1);
        }
        bf16x8 a[4], b[4];
#pragma unroll
        for (int m = 0; m < 4; ++m) a[m] = *(const bf16x8*)&As[cur][rdA + m * 512];
#pragma unroll
        for (int n = 0; n < 4; ++n) b[n] = *(const bf16x8*)&Bs[cur][rdB + n * 512];
        __builtin_amdgcn_s_setprio(1);
#pragma unroll
        for (int i = 0; i < 4; ++i)
#pragma unroll
            for (int j = 0; j < 4; ++j)
                acc[i][j] = __builtin_amdgcn_mfma_f32_16x16x32_bf16(a[i], b[j], acc[i][j], 0, 0, 0);
        __builtin_amdgcn_s_setprio(0);
        WAITV0();
        BARX();
        cur ^= 1;
    }

#undef BARX
#undef WAITV0
#undef STG

    int f = (EPI == 1 || EPI == 2 || EPI == 4) ? *fl : 0;
    const int col0 = n0 + wn * 64 + (lane & 15);
    const int row0 = m0 + wm * 64 + ((lane >> 4) << 2);
#pragma unroll
    for (int i = 0; i < 4; ++i) {
#pragma unroll
        for (int r = 0; r < 4; ++r) {
            int row = row0 + i * 16 + r;
            size_t base = (size_t)row * N;
#pragma unroll
            for (int j = 0; j < 4; ++j) {
                int col = col0 + j * 16;
                float v = acc[i][j][r];
                if (EPI == 0) {
                    ((u16*)out)[base + col] = f2bf(v);
                } else if (EPI == 1) {
                    ((u16*)out)[base + col] = f2bf(sigmoidf_(v + ld1f(aux, col, f)));
                } else if (EPI == 2) {
                    ((u16*)out)[base + col] = f2bf(v + ld1f(aux, base + col, f));
                } else if (EPI == 3) {
                    float g = bf2f(((const u16*)aux)[base + col]);
                    ((u16*)out)[base + col] = f2bf(g * sigmoidf_(g) * v);
                } else {
                    float hr = bf2f(((const u16*)aux)[base + col]);
                    if (f) ((float*)out)[oofs + base + col] = v + hr;
                    else   ((u16*)out)[oofs + base + col] = f2bf(v + hr);
                }
            }
        }
    }
}

// ---------------- per-head l2norm (in place) ----------------
__global__ __launch_bounds__(256) void l2norm_k(u16* __restrict__ x) {
    int m = blockIdx.x, tid = threadIdx.x;
    size_t base = (size_t)m * D_MODEL + tid * 8;
    uint4 p = *(const uint4*)&x[base];
    float v[8];
    unpack8(p, v);
    float s = 0.f;
#pragma unroll
    for (int i = 0; i < 8; ++i) s += v[i] * v[i];
    s += __shfl_xor(s, 1, 64); s += __shfl_xor(s, 2, 64);
    s += __shfl_xor(s, 4, 64); s += __shfl_xor(s, 8, 64);
    float sc = rsqrtf(s + 1e-12f);
    float o[8];
#pragma unroll
    for (int i = 0; i < 8; ++i) o[i] = v[i] * sc;
    *(uint4*)&x[base] = pack8(o);
}

// ---------------- per-head LayerNorm (in place), D=128 ----------------
__global__ __launch_bounds__(256) void vnorm_k(u16* __restrict__ x, const void* __restrict__ w,
                                               const void* __restrict__ bb, const int* __restrict__ fl) {
    int f = *fl;
    int m = blockIdx.x, tid = threadIdx.x;
    size_t base = (size_t)m * D_MODEL + tid * 8;
    uint4 p = *(const uint4*)&x[base];
    float v[8];
    unpack8(p, v);
    float s = 0.f, ss = 0.f;
#pragma unroll
    for (int i = 0; i < 8; ++i) { s += v[i]; ss += v[i] * v[i]; }
    s += __shfl_xor(s, 1, 64); s += __shfl_xor(s, 2, 64);
    s += __shfl_xor(s, 4, 64); s += __shfl_xor(s, 8, 64);
    ss += __shfl_xor(ss, 1, 64); ss += __shfl_xor(ss, 2, 64);
    ss += __shfl_xor(ss, 4, 64); ss += __shfl_xor(ss, 8, 64);
    float mu = s * (1.f / HEADDIM);
    float var = ss * (1.f / HEADDIM) - mu * mu;
    float rs = rsqrtf(var + 1e-5f);
    int d0 = (tid * 8) & 127;
    float o[8];
#pragma unroll
    for (int i = 0; i < 8; ++i) o[i] = (v[i] - mu) * rs * ld1f(w, d0 + i, f) + ld1f(bb, d0 + i, f);
    *(uint4*)&x[base] = pack8(o);
}

// ---------------- gamma[m,h] = sigmoid(xc[m,:] @ Wg[:,h] + bg[h]) ----------------
__global__ __launch_bounds__(256) void gamma_k(const u16* __restrict__ xc, const void* __restrict__ Wg,
                                               const void* __restrict__ bg, float* __restrict__ gamma,
                                               const int* __restrict__ fl) {
    int f = *fl;
    int m = blockIdx.x, tid = threadIdx.x;
    float g[16];
#pragma unroll
    for (int h = 0; h < 16; ++h) g[h] = 0.f;
    size_t base = (size_t)m * D_MODEL + tid * 8;
    uint4 xp = *(const uint4*)&xc[base];
    float xv[8];
    unpack8(xp, xv);
#pragma unroll
    for (int i = 0; i < 8; ++i) {
        float wv[16];
        size_t ro = (size_t)(tid * 8 + i) * 16;
        if (f) {
            const float4* wr = (const float4*)((const float*)Wg + ro);
#pragma unroll
            for (int q = 0; q < 4; ++q) {
                float4 w4 = wr[q];
                wv[q * 4 + 0] = w4.x; wv[q * 4 + 1] = w4.y; wv[q * 4 + 2] = w4.z; wv[q * 4 + 3] = w4.w;
            }
        } else {
            const u16* wrow = (const u16*)Wg + ro;
            uint4 w0 = *(const uint4*)&wrow[0];
            uint4 w1 = *(const uint4*)&wrow[8];
            unpack8(w0, wv);
            unpack8(w1, wv + 8);
        }
#pragma unroll
        for (int h = 0; h < 16; ++h) g[h] += xv[i] * wv[h];
    }
#pragma unroll
    for (int h = 0; h < 16; ++h)
#pragma unroll
        for (int off = 32; off; off >>= 1) g[h] += __shfl_xor(g[h], off, 64);
    __shared__ float part[4][16];
    int lane = tid & 63, wvi = tid >> 6;
    if (lane == 0)
#pragma unroll
        for (int h = 0; h < 16; ++h) part[wvi][h] = g[h];
    __syncthreads();
    if (tid < 16) {
        float s = part[0][tid] + part[1][tid] + part[2][tid] + part[3][tid] + ld1f(bg, tid, f);
        gamma[(size_t)m * 16 + tid] = sigmoidf_(s);
    }
}

// ---------------- chunked gated scan, phase 1: local scans + prefix products ----------------
__global__ __launch_bounds__(256) void scan1(const u16* __restrict__ ig, const u16* __restrict__ kn,
                                             const u16* __restrict__ vn, const float* __restrict__ gamma,
                                             float* __restrict__ mem, float* __restrict__ pp) {
    int idx = blockIdx.x;              // B * NCHUNK * 8
    int cblk = idx & 7, ch = (idx >> 3) & (NCHUNK - 1), b = idx >> 8;
    int c = cblk * 256 + threadIdx.x;
    int h = c >> 7;
    float mval = 0.f, p = 1.f;
    int t0 = ch * CHUNK;
    size_t rowbase = ((size_t)(b * TLEN + t0)) * D_MODEL + c;
    size_t grow = (size_t)(b * TLEN + t0) * 16 + h;
    bool writepp = ((c & 127) == 0);
    for (int s = 0; s < CHUNK; ++s) {
        float u = bf2f(ig[rowbase]) * bf2f(kn[rowbase]) * bf2f(vn[rowbase]);
        float g = gamma[grow];
        mval = g * mval + u;
        p *= g;
        mem[rowbase] = mval;
        if (writepp) pp[grow] = p;
        rowbase += D_MODEL;
        grow += 16;
    }
}

// ---------------- phase 2: serial carry across chunks ----------------
__global__ __launch_bounds__(256) void scan2(const float* __restrict__ mem, const float* __restrict__ pp,
                                             float* __restrict__ carry) {
    int idx = blockIdx.x * 256 + threadIdx.x;  // B*C = 4096
    int b = idx >> 11, c = idx & 2047, h = c >> 7;
    float cy = 0.f;
    for (int ch = 0; ch < NCHUNK; ++ch) {
        carry[((size_t)(b * NCHUNK + ch)) * D_MODEL + c] = cy;
        int tend = ch * CHUNK + CHUNK - 1;
        float P = pp[((size_t)(b * TLEN + tend)) * 16 + h];
        float le = mem[((size_t)(b * TLEN + tend)) * D_MODEL + c];
        cy = P * cy + le;
    }
}

// ---------------- attn epilogue: carry-fix + LN(mem)*q -> GroupNorm -> *og ----------------
__global__ __launch_bounds__(256) void attn_epi(const float* __restrict__ mem, const float* __restrict__ pp,
                                                const float* __restrict__ carry, const u16* __restrict__ qn,
                                                const u16* __restrict__ og, const void* __restrict__ mnw,
                                                const void* __restrict__ mnb, const void* __restrict__ gnw,
                                                const void* __restrict__ gnb, u16* __restrict__ outb,
                                                const int* __restrict__ fl) {
    int f = *fl;
    int m = blockIdx.x, tid = threadIdx.x;
    int b = m >> 12, t = m & (TLEN - 1);
    int ch = t >> 7;
    int c = tid * 8, h = c >> 7;
    size_t base = (size_t)m * D_MODEL + c;
    float mv[8];
    {
        const float4* p = (const float4*)&mem[base];
        float4 a = p[0], bb4 = p[1];
        mv[0] = a.x; mv[1] = a.y; mv[2] = a.z; mv[3] = a.w;
        mv[4] = bb4.x; mv[5] = bb4.y; mv[6] = bb4.z; mv[7] = bb4.w;
    }
    float ppv = pp[(size_t)m * 16 + h];
    {
        const float4* p = (const float4*)&carry[((size_t)(b * NCHUNK + ch)) * D_MODEL + c];
        float4 a = p[0], bb4 = p[1];
        mv[0] += ppv * a.x; mv[1] += ppv * a.y; mv[2] += ppv * a.z; mv[3] += ppv * a.w;
        mv[4] += ppv * bb4.x; mv[5] += ppv * bb4.y; mv[6] += ppv * bb4.z; mv[7] += ppv * bb4.w;
    }
    float s = 0.f, ss = 0.f;
#pragma unroll
    for (int i = 0; i < 8; ++i) { s += mv[i]; ss += mv[i] * mv[i]; }
    s += __shfl_xor(s, 1, 64); s += __shfl_xor(s, 2, 64);
    s += __shfl_xor(s, 4, 64); s += __shfl_xor(s, 8, 64);
    ss += __shfl_xor(ss, 1, 64); ss += __shfl_xor(ss, 2, 64);
    ss += __shfl_xor(ss, 4, 64); ss += __shfl_xor(ss, 8, 64);
    float mu = s * (1.f / HEADDIM);
    float var = ss * (1.f / HEADDIM) - mu * mu;
    float rs = rsqrtf(var + 1e-5f);
    int d0 = c & 127;
    uint4 qp = *(const uint4*)&qn[base];
    float qv[8];
    unpack8(qp, qv);
    float o[8];
#pragma unroll
    for (int i = 0; i < 8; ++i)
        o[i] = ((mv[i] - mu) * rs * ld1f(mnw, d0 + i, f) + ld1f(mnb, d0 + i, f)) * qv[i];
    float s2 = 0.f, ss2 = 0.f;
#pragma unroll
    for (int i = 0; i < 8; ++i) { s2 += o[i]; ss2 += o[i] * o[i]; }
    s2 += __shfl_xor(s2, 1, 64); s2 += __shfl_xor(s2, 2, 64);
    s2 += __shfl_xor(s2, 4, 64); s2 += __shfl_xor(s2, 8, 64);
    ss2 += __shfl_xor(ss2, 1, 64); ss2 += __shfl_xor(ss2, 2, 64);
    ss2 += __shfl_xor(ss2, 4, 64); ss2 += __shfl_xor(ss2, 8, 64);
    float mu2 = s2 * (1.f / HEADDIM);
    float var2 = ss2 * (1.f / HEADDIM) - mu2 * mu2;
    float rs2 = rsqrtf(var2 + 1e-5f);
    uint4 ogp = *(const uint4*)&og[base];
    float ogv[8];
    unpack8(ogp, ogv);
    float ob[8];
#pragma unroll
    for (int i = 0; i < 8; ++i)
        ob[i] = ((o[i] - mu2) * rs2 * ld1f(gnw, c + i, f) + ld1f(gnb, c + i, f)) * ogv[i];
    *(uint4*)&outb[base] = pack8(ob);
}

// ---------------- workspace arena: 8 slots x 32 MiB = 256 MiB peak ----------------
// slot0: wT (8 MiB, reused) + gamma/pp/carry/flagA @16MiB -> wTgate (32 MiB, MLP)
// slot1: hb      -> mem[lo]  -> wTval
// slot2: xcb     -> mem[hi]  -> wTout
// slot3: qn      -> h2b
// slot4: kn      -> attn     -> flagB (MLP phase)
// slot5: vn      -> hres (bf16)
// slot6: ig      -> graw[lo]
// slot7: og      -> graw[hi]
#define SLOT 33554432ull
#define WS_NEED (SLOT * 8)
#define FLAGA_OFF 18350080ull   /* slot0 + 16MiB + 1.5MiB (after carry) */
#define FLAGB_OFF (SLOT * 4)

extern "C" void kernel_launch(void* const* d_in, const int* in_sizes, int n_in,
                              void* d_out, int out_size, void* d_ws, size_t ws_size,
                              hipStream_t stream) {
    if (ws_size < WS_NEED) return;  // diagnostic guard: fail absmax instead of crashing

    const void* x     = d_in[0];
    const void* Wq    = d_in[1];
    const void* Wk    = d_in[2];
    const void* Wv    = d_in[3];
    const void* Wo    = d_in[4];
    const void* convw = d_in[5];
    const void* convb = d_in[6];
    const void* Wig   = d_in[7];
    const void* big   = d_in[8];
    const void* Wog   = d_in[9];
    const void* bog   = d_in[10];
    const void* Wg    = d_in[11];
    const void* bg    = d_in[12];
    const void* vnw   = d_in[13];
    const void* vnb   = d_in[14];
    const void* mnw   = d_in[15];
    const void* mnb   = d_in[16];
    const void* gnw   = d_in[17];
    const void* gnb   = d_in[18];
    const void* ln1w  = d_in[19];
    const void* ln1b  = d_in[20];
    const void* ln2w  = d_in[21];
    const void* ln2b  = d_in[22];
    const void* Wgate = d_in[23];
    const void* Wval  = d_in[24];
    const void* Wout  = d_in[25];

    char* ws = (char*)d_ws;
    u16* wT      = (u16*)(ws);
    float* gamma = (float*)(ws + 16777216);
    float* pp    = (float*)(ws + 16777216 + 524288);
    float* carry = (float*)(ws + 16777216 + 1048576);
    int* flagA   = (int*)(ws + FLAGA_OFF);
    int* flagB   = (int*)(ws + FLAGB_OFF);
    u16* hb      = (u16*)(ws + SLOT * 1);
    u16* xcb     = (u16*)(ws + SLOT * 2);
    float* mem   = (float*)(ws + SLOT * 1);          // spans slots 1-2 (f32)
    u16* wTgate  = (u16*)(ws);                       // slot0 (32 MiB), MLP phase
    u16* wTval   = (u16*)(ws + SLOT * 1);
    u16* wTout   = (u16*)(ws + SLOT * 2);
    u16* qn      = (u16*)(ws + SLOT * 3);
    u16* h2b     = (u16*)(ws + SLOT * 3);
    u16* kn      = (u16*)(ws + SLOT * 4);
    u16* attn    = (u16*)(ws + SLOT * 4);
    u16* vn      = (u16*)(ws + SLOT * 5);
    u16* hres    = (u16*)(ws + SLOT * 5);
    u16* ig      = (u16*)(ws + SLOT * 6);
    u16* og      = (u16*)(ws + SLOT * 7);
    u16* graw    = (u16*)(ws + SLOT * 6);            // spans slots 6-7

    dim3 tb(32, 8);

    detect_k<<<1, 256, 0, stream>>>((const u16*)x, flagA);

    // ---- attention front-end ----
    ln_rows<1><<<MTOK, 256, 0, stream>>>(x, hb, ln1w, ln1b, flagA);
    conv_silu_k<<<MTOK, 256, 0, stream>>>(hb, convw, convb, xcb, flagA);

    transpose_k<<<dim3(64, 64), tb, 0, stream>>>(Wq, wT, 2048, 2048, flagA);
    gemmT<0><<<dim3(16, 64), 256, 0, stream>>>(hb, wT, qn, nullptr, nullptr, 0, MTOK, 2048, 2048);
    transpose_k<<<dim3(64, 64), tb, 0, stream>>>(Wk, wT, 2048, 2048, flagA);
    gemmT<0><<<dim3(16, 64), 256, 0, stream>>>(hb, wT, kn, nullptr, nullptr, 0, MTOK, 2048, 2048);
    transpose_k<<<dim3(64, 64), tb, 0, stream>>>(Wv, wT, 2048, 2048, flagA);
    gemmT<0><<<dim3(16, 64), 256, 0, stream>>>(hb, wT, vn, nullptr, nullptr, 0, MTOK, 2048, 2048);
    l2norm_k<<<MTOK, 256, 0, stream>>>(qn);
    l2norm_k<<<MTOK, 256, 0, stream>>>(kn);
    vnorm_k<<<MTOK, 256, 0, stream>>>(vn, vnw, vnb, flagA);

    transpose_k<<<dim3(64, 64), tb, 0, stream>>>(Wig, wT, 2048, 2048, flagA);
    gemmT<1><<<dim3(16, 64), 256, 0, stream>>>(xcb, wT, ig, big, flagA, 0, MTOK, 2048, 2048);
    transpose_k<<<dim3(64, 64), tb, 0, stream>>>(Wog, wT, 2048, 2048, flagA);
    gemmT<1><<<dim3(16, 64), 256, 0, stream>>>(xcb, wT, og, bog, flagA, 0, MTOK, 2048, 2048);
    gamma_k<<<MTOK, 256, 0, stream>>>(xcb, Wg, bg, gamma, flagA);

    // ---- gated scan (mem overwrites hb/xcb slots — both dead) ----
    scan1<<<BSZ * NCHUNK * 8, 256, 0, stream>>>(ig, kn, vn, gamma, mem, pp);
    scan2<<<16, 256, 0, stream>>>(mem, pp, carry);
    attn_epi<<<MTOK, 256, 0, stream>>>(mem, pp, carry, qn, og, mnw, mnb, gnw, gnb, attn, flagA);

    // ---- output projection + residual (hres bf16) ----
    transpose_k<<<dim3(64, 64), tb, 0, stream>>>(Wo, wT, 2048, 2048, flagA);
    gemmT<2><<<dim3(16, 64), 256, 0, stream>>>(attn, wT, hres, x, flagA, 0, MTOK, 2048, 2048);
    ln_rows<0><<<MTOK, 256, 0, stream>>>(hres, h2b, ln2w, ln2b, flagA);

    // ---- flag to MLP-phase home (slot4 free after Wo gemm) ----
    copyflag_k<<<1, 1, 0, stream>>>(flagA, flagB);

    // ---- MLP: transpose all three weights once, then two M=4096 halves ----
    transpose_k<<<dim3(256, 64), tb, 0, stream>>>(Wgate, wTgate, 2048, 8192, flagB);
    transpose_k<<<dim3(256, 64), tb, 0, stream>>>(Wval, wTval, 2048, 8192, flagB);
    transpose_k<<<dim3(64, 256), tb, 0, stream>>>(Wout, wTout, 8192, 2048, flagB);

    for (int half = 0; half < 2; ++half) {
        const u16* a2 = h2b + (size_t)half * 4096 * 2048;
        const u16* hr = hres + (size_t)half * 4096 * 2048;
        long long oofs = (long long)half * 4096 * 2048;
        gemmT<0><<<dim3(64, 32), 256, 0, stream>>>(a2, wTgate, graw, nullptr, nullptr, 0, 4096, 8192, 2048);
        gemmT<3><<<dim3(64, 32), 256, 0, stream>>>(a2, wTval, graw, graw, nullptr, 0, 4096, 8192, 2048);
        gemmT<4><<<dim3(16, 32), 256, 0, stream>>>(graw, wTout, d_out, hr, flagB, oofs, 4096, 2048, 8192);
    }
}